// Round 8
// baseline (335.928 us; speedup 1.0000x reference)
//
#include <hip/hip_runtime.h>
#include <math.h>

// Problem constants (fixed by reference: B=32,T=1024,D=256,K=1024)
#define N_ROWS 32768
#define DIM    256
#define KCODES 1024
// Screen is single-pass bf16 (s~ = e2 - 2*xh.eh). Score error: sigma ~2.8e-5,
// max over 3.4e7 samples ~1.5e-4; plus numpy fp32 rounding band ~6e-5.
// DELTA = 5e-4 covers flips at >10 sigma; ambiguous rows get exact fp32
// rescore (R2-proven numpy-rounding path).
#define DELTA  5.0e-4f

typedef float f32x4 __attribute__((ext_vector_type(4)));
typedef short s16x8 __attribute__((ext_vector_type(8)));

__device__ inline unsigned short bf_rne(float f) {
    unsigned u = __float_as_uint(f);
    return (unsigned short)((u + 0x7FFFu + ((u >> 16) & 1u)) >> 16);
}

// BRANCHLESS lex sorted-insert of (v,ix) into ascending top-4 (ties -> lower
// index). Compare-exchange walk; result = sorted lex-top-4 of the values seen,
// identical to the old nested-if ins4 (both insertion-order independent).
// R7 post-mortem: the nested-if version compiled to divergent exec-mask branch
// ladders (SALU churn at 25% VALUBusy); this is pure cndmask.
__device__ inline void ins4(float v, int ix, float (&tv)[4], int (&ti)[4]) {
#pragma unroll
    for (int s = 0; s < 4; ++s) {
        bool better = (v < tv[s]) || (v == tv[s] && ix < ti[s]);
        float dv = better ? tv[s] : v;   // displaced element continues down
        int   di = better ? ti[s] : ix;
        tv[s] = better ? v : tv[s];
        ti[s] = better ? ix : ti[s];
        v = dv; ix = di;
    }
}

// ---------------------------------------------------------------------------
// E prep only (e2 pairwise + bf16 hi of E) — verbatim R2-proven body.
__global__ __launch_bounds__(256) void prep_kernel(const float* __restrict__ E,
                                                   float* __restrict__ e2,
                                                   unsigned short* __restrict__ Eh) {
    __shared__ float sq[4][260];
    const int wave = threadIdx.x >> 6;
    const int lane = threadIdx.x & 63;
    const int row = blockIdx.x * 4 + wave;
    const float4* rp = (const float4*)(E + (size_t)row * DIM);
    float4 v = rp[lane];
    sq[wave][lane * 4 + 0] = v.x * v.x;
    sq[wave][lane * 4 + 1] = v.y * v.y;
    sq[wave][lane * 4 + 2] = v.z * v.z;
    sq[wave][lane * 4 + 3] = v.w * v.w;
    float fs[4] = {v.x, v.y, v.z, v.w};
    ushort4 hv;
    unsigned short* hp = (unsigned short*)&hv;
#pragma unroll
    for (int j = 0; j < 4; ++j) hp[j] = bf_rne(fs[j]);
    *(ushort4*)(Eh + (size_t)row * DIM + lane * 4) = hv;
    if (lane < 8) {
#pragma clang fp contract(off)
        const int j = lane;
        float rA = sq[wave][j];
#pragma unroll
        for (int m = 1; m < 16; ++m) rA += sq[wave][8 * m + j];
        float rB = sq[wave][128 + j];
#pragma unroll
        for (int m = 1; m < 16; ++m) rB += sq[wave][128 + 8 * m + j];
        rA = rA + __shfl_xor(rA, 1, 64); rA = rA + __shfl_xor(rA, 2, 64);
        rA = rA + __shfl_xor(rA, 4, 64);
        rB = rB + __shfl_xor(rB, 1, 64); rB = rB + __shfl_xor(rB, 2, 64);
        rB = rB + __shfl_xor(rB, 4, 64);
        if (j == 0) e2[row] = rA + rB;
    }
}

// Exact serial replica of the wave-parallel numpy-pairwise row sum-of-squares.
__device__ float x2_exact(const float* __restrict__ xr) {
#pragma clang fp contract(off)
    float rr[16];
#pragma unroll
    for (int j = 0; j < 8; ++j) {
        float a = xr[j] * xr[j];
#pragma unroll
        for (int m = 1; m < 16; ++m) { float t = xr[8 * m + j]; float s = t * t; a += s; }
        rr[j] = a;
        float b = xr[128 + j] * xr[128 + j];
#pragma unroll
        for (int m = 1; m < 16; ++m) { float t = xr[128 + 8 * m + j]; float s = t * t; b += s; }
        rr[8 + j] = b;
    }
    float a01 = rr[0] + rr[1], a23 = rr[2] + rr[3];
    float a45 = rr[4] + rr[5], a67 = rr[6] + rr[7];
    float A = (a01 + a23) + (a45 + a67);
    float b01 = rr[8] + rr[9], b23 = rr[10] + rr[11];
    float b45 = rr[12] + rr[13], b67 = rr[14] + rr[15];
    float Bt = (b01 + b23) + (b45 + b67);
    return A + Bt;
}

// ---------------------------------------------------------------------------
// Fused screen + decide + gather — R7 structure at the CORRECT register point.
// R7 failed because __launch_bounds__(256,6) forced a 40-VGPR budget and the
// allocator spilled xh[8] into the inner loop (~1 GB scratch reloads).
// Here: __launch_bounds__(256,4) -> 128-VGPR cap (empirically safe, R5/R6);
// kernel genuinely needs ~90-110 -> no spill, residency 5 waves/SIMD by VGPR.
// 256 thr = 4 waves, 16 rows/block; wave w owns code quarter w. Direct-L2
// code-fragment loads (R6-proven bit-identical layout), barrier-free main
// loop, per-block tile rotation. MFMA accumulation split even/odd ks (2-way
// matrix-pipe ILP; changes the approx screen score by ~1 ulp, irrelevant vs
// DELTA; exact rescue path untouched). Branchless ins4 (see above).
__global__ __launch_bounds__(256, 4) void vq_fused_kernel(const float* __restrict__ X,
                                                          const unsigned short* __restrict__ Eh,
                                                          const float* __restrict__ e2g,
                                                          const float* __restrict__ E,
                                                          float* __restrict__ out0,
                                                          float* __restrict__ out1,
                                                          float* __restrict__ out2) {
    __shared__ float mv[48 * 4];   // 3 quarters x 16 rows x top4
    __shared__ int   mi[48 * 4];
    __shared__ int   sidx[16];

    const int tid  = threadIdx.x;
    const int w    = tid >> 6;     // code quarter 0..3
    const int l    = tid & 63;
    const int c16  = l & 15;
    const int quad = l >> 4;
    const int row0 = blockIdx.x * 16;

    // ---- X fragments (B-operand): 16 rows, hi only, K=256 (32 VGPR) ----
    s16x8 xh[8];
    {
        const float* xrow = X + (size_t)(row0 + c16) * DIM + quad * 8;
#pragma unroll
        for (int ks = 0; ks < 8; ++ks) {
            float4 f0 = *(const float4*)(xrow + ks * 32);
            float4 f1 = *(const float4*)(xrow + ks * 32 + 4);
            float fs[8] = {f0.x, f0.y, f0.z, f0.w, f1.x, f1.y, f1.z, f1.w};
#pragma unroll
            for (int j = 0; j < 8; ++j) xh[ks][j] = (short)bf_rne(fs[j]);
        }
    }

    float tva[4];
    int   tia[4];
#pragma unroll
    for (int s = 0; s < 4; ++s) { tva[s] = INFINITY; tia[s] = 0x7fffffff; }

    // ---- main loop: 16 code-tiles of this wave's quarter, no barriers ----
    const int rot = blockIdx.x & 15;
    for (int t0 = 0; t0 < 16; ++t0) {
        const int c = (t0 + rot) & 15;
        const int base = c * 64 + w * 16;
        // A-fragments for codes [base, base+16): lane holds A[m=c16][k=quad*8+j]
        const unsigned short* ep = Eh + (size_t)(base + c16) * DIM + quad * 8;
        s16x8 ch[8];
#pragma unroll
        for (int ks = 0; ks < 8; ++ks) ch[ks] = *(const s16x8*)(ep + ks * 32);
        f32x4 ce = {0.f, 0.f, 0.f, 0.f};
        f32x4 co = {0.f, 0.f, 0.f, 0.f};
#pragma unroll
        for (int ks = 0; ks < 8; ks += 2) {
            ce = __builtin_amdgcn_mfma_f32_16x16x32_bf16(ch[ks],     xh[ks],     ce, 0, 0, 0);
            co = __builtin_amdgcn_mfma_f32_16x16x32_bf16(ch[ks + 1], xh[ks + 1], co, 0, 0, 0);
        }
        f32x4 e2v = *(const f32x4*)(e2g + base + quad * 4);
#pragma unroll
        for (int r = 0; r < 4; ++r) {
            const int code = base + quad * 4 + r;
            ins4(fmaf(-2.0f, ce[r] + co[r], e2v[r]), code, tva, tia);
        }
    }

    // merge top-4 across the 4 quads holding the same x-row (lanes l^16, l^32)
#pragma unroll
    for (int st = 16; st <= 32; st <<= 1) {
        float ov[4]; int oi[4];
#pragma unroll
        for (int s = 0; s < 4; ++s) {
            ov[s] = __shfl_xor(tva[s], st, 64);
            oi[s] = __shfl_xor(tia[s], st, 64);
        }
#pragma unroll
        for (int s = 0; s < 4; ++s) ins4(ov[s], oi[s], tva, tia);
    }

    // merge the 4 code-quarters (exact, order-independent lex top-4) via LDS
    if (w >= 1 && quad == 0) {
        const int sa = (w - 1) * 16 + c16;
#pragma unroll
        for (int s = 0; s < 4; ++s) { mv[sa * 4 + s] = tva[s]; mi[sa * 4 + s] = tia[s]; }
    }
    __syncthreads();
    if (w == 0 && quad == 0) {
#pragma unroll
        for (int g2 = 0; g2 < 3; ++g2) {
            const int sa = g2 * 16 + c16;
#pragma unroll
            for (int s = 0; s < 4; ++s) ins4(mv[sa * 4 + s], mi[sa * 4 + s], tva, tia);
        }
        // ---- decide this row (verbatim R2-proven logic; x2 recomputed
        //      exactly in the rescue path only) ----
        const int r = row0 + c16;
        int best = tia[0];
        if (!(tva[1] > tva[0] + DELTA)) {
            const float* xr = X + (size_t)r * DIM;
            const float x2v = x2_exact(xr);
            float bq = INFINITY; int bi = 0x7fffffff;
            for (int cnd = 0; cnd < 4; ++cnd) {
                if (tva[cnd] <= tva[0] + DELTA) {
                    const int k = tia[cnd];
                    const float* er = E + (size_t)k * DIM;
                    float dot = 0.f;
                    for (int d = 0; d < DIM; d += 4) {   // sequential fp32 chain
                        float4 xv = *(const float4*)(xr + d);
                        float4 ev = *(const float4*)(er + d);
                        dot = fmaf(xv.x, ev.x, dot);
                        dot = fmaf(xv.y, ev.y, dot);
                        dot = fmaf(xv.z, ev.z, dot);
                        dot = fmaf(xv.w, ev.w, dot);
                    }
                    float t1 = e2g[k] - 2.0f * dot;   // numpy elementwise rounding
                    float q  = t1 + x2v;
                    if (q < bq || (q == bq && k < bi)) { bq = q; bi = k; }
                }
            }
            best = bi;
        }
        sidx[c16] = best;
        out2[r] = (float)best;
    }
    __syncthreads();

    // ---- gather epilogue: 16 rows, coalesced float4 writes ----
#pragma unroll
    for (int it = 0; it < 4; ++it) {
        int f = tid + it * 256;
        int rr = f >> 6;
        int pp = f & 63;
        int ix = sidx[rr];
        float4 v = *(const float4*)(E + (size_t)ix * DIM + pp * 4);
        size_t o = (size_t)(row0 + rr) * DIM + (size_t)pp * 4;
        *(float4*)(out0 + o) = v;
        *(float4*)(out1 + o) = v;
    }
}

// ---------------------------------------------------------------------------
extern "C" void kernel_launch(void* const* d_in, const int* in_sizes, int n_in,
                              void* d_out, int out_size, void* d_ws, size_t ws_size,
                              hipStream_t stream) {
    const float* X = (const float*)d_in[0];
    const float* E = (const float*)d_in[1];

    // ws layout (all 16B-aligned): ~0.53 MB total
    float* e2 = (float*)d_ws;                              // 1024 f
    unsigned short* Eh = (unsigned short*)(e2 + KCODES);   // 262144 us

    float* out0 = (float*)d_out;
    float* out1 = out0 + (size_t)N_ROWS * DIM;
    float* out2 = out1 + (size_t)N_ROWS * DIM;

    prep_kernel<<<dim3(KCODES / 4), dim3(256), 0, stream>>>(E, e2, Eh);
    vq_fused_kernel<<<dim3(N_ROWS / 16), dim3(256), 0, stream>>>(X, Eh, e2, E,
                                                                 out0, out1, out2);
}

// Round 9
// 259.071 us; speedup vs baseline: 1.2967x; 1.2967x over previous
//
#include <hip/hip_runtime.h>
#include <math.h>

// Problem constants (fixed by reference: B=32,T=1024,D=256,K=1024)
#define N_ROWS 32768
#define DIM    256
#define KCODES 1024
// Screen is single-pass bf16 (s~ = e2 - 2*xh.eh). Score error: sigma ~2.8e-5,
// max over 3.4e7 samples ~1.5e-4; plus numpy fp32 rounding band ~6e-5.
// DELTA = 5e-4 covers flips at >10 sigma; ambiguous rows get exact fp32
// rescore (R2-proven numpy-rounding path).
#define DELTA  5.0e-4f

typedef float f32x4 __attribute__((ext_vector_type(4)));
typedef short s16x8 __attribute__((ext_vector_type(8)));

__device__ inline unsigned short bf_rne(float f) {
    unsigned u = __float_as_uint(f);
    return (unsigned short)((u + 0x7FFFu + ((u >> 16) & 1u)) >> 16);
}

// BRANCHLESS lex sorted-insert of (v,ix) into ascending top-4 (ties -> lower
// index). Compare-exchange walk; insertion-order independent, identical result
// to the original nested-if version.
__device__ inline void ins4(float v, int ix, float (&tv)[4], int (&ti)[4]) {
#pragma unroll
    for (int s = 0; s < 4; ++s) {
        bool better = (v < tv[s]) || (v == tv[s] && ix < ti[s]);
        float dv = better ? tv[s] : v;   // displaced element continues down
        int   di = better ? ti[s] : ix;
        tv[s] = better ? v : tv[s];
        ti[s] = better ? ix : ti[s];
        v = dv; ix = di;
    }
}

// ---------------------------------------------------------------------------
// E prep only (e2 pairwise + bf16 hi of E) — verbatim R2-proven body.
__global__ __launch_bounds__(256) void prep_kernel(const float* __restrict__ E,
                                                   float* __restrict__ e2,
                                                   unsigned short* __restrict__ Eh) {
    __shared__ float sq[4][260];
    const int wave = threadIdx.x >> 6;
    const int lane = threadIdx.x & 63;
    const int row = blockIdx.x * 4 + wave;
    const float4* rp = (const float4*)(E + (size_t)row * DIM);
    float4 v = rp[lane];
    sq[wave][lane * 4 + 0] = v.x * v.x;
    sq[wave][lane * 4 + 1] = v.y * v.y;
    sq[wave][lane * 4 + 2] = v.z * v.z;
    sq[wave][lane * 4 + 3] = v.w * v.w;
    float fs[4] = {v.x, v.y, v.z, v.w};
    ushort4 hv;
    unsigned short* hp = (unsigned short*)&hv;
#pragma unroll
    for (int j = 0; j < 4; ++j) hp[j] = bf_rne(fs[j]);
    *(ushort4*)(Eh + (size_t)row * DIM + lane * 4) = hv;
    if (lane < 8) {
#pragma clang fp contract(off)
        const int j = lane;
        float rA = sq[wave][j];
#pragma unroll
        for (int m = 1; m < 16; ++m) rA += sq[wave][8 * m + j];
        float rB = sq[wave][128 + j];
#pragma unroll
        for (int m = 1; m < 16; ++m) rB += sq[wave][128 + 8 * m + j];
        rA = rA + __shfl_xor(rA, 1, 64); rA = rA + __shfl_xor(rA, 2, 64);
        rA = rA + __shfl_xor(rA, 4, 64);
        rB = rB + __shfl_xor(rB, 1, 64); rB = rB + __shfl_xor(rB, 2, 64);
        rB = rB + __shfl_xor(rB, 4, 64);
        if (j == 0) e2[row] = rA + rB;
    }
}

// Exact serial replica of the wave-parallel numpy-pairwise row sum-of-squares.
__device__ float x2_exact(const float* __restrict__ xr) {
#pragma clang fp contract(off)
    float rr[16];
#pragma unroll
    for (int j = 0; j < 8; ++j) {
        float a = xr[j] * xr[j];
#pragma unroll
        for (int m = 1; m < 16; ++m) { float t = xr[8 * m + j]; float s = t * t; a += s; }
        rr[j] = a;
        float b = xr[128 + j] * xr[128 + j];
#pragma unroll
        for (int m = 1; m < 16; ++m) { float t = xr[128 + 8 * m + j]; float s = t * t; b += s; }
        rr[8 + j] = b;
    }
    float a01 = rr[0] + rr[1], a23 = rr[2] + rr[3];
    float a45 = rr[4] + rr[5], a67 = rr[6] + rr[7];
    float A = (a01 + a23) + (a45 + a67);
    float b01 = rr[8] + rr[9], b23 = rr[10] + rr[11];
    float b45 = rr[12] + rr[13], b67 = rr[14] + rr[15];
    float Bt = (b01 + b23) + (b45 + b67);
    return A + Bt;
}

// ---------------------------------------------------------------------------
// SCREEN ONLY (R9 split). R8 post-mortem: the fused per-block decide tail ran
// on 16 lanes of one wave while all other waves waited at __syncthreads —
// a multi-us serial tail per block, serialized across resident blocks. That
// (not the main loop) was the dominant cost since R3. This kernel ends at
// topv/topi; decide+gather moved to a thread-per-row kernel (R2's structure,
// whose rescue path runs 64-wide SIMT-parallel).
// 256 thr = 4 waves, 16 rows/block; wave w owns code quarter w. Direct-L2
// code-fragment loads (R6-proven layout), barrier-free main loop, per-block
// tile rotation, even/odd MFMA split, branchless ins4.
__global__ __launch_bounds__(256, 4) void vq_screen_kernel(const float* __restrict__ X,
                                                           const unsigned short* __restrict__ Eh,
                                                           const float* __restrict__ e2g,
                                                           float* __restrict__ topv,
                                                           int* __restrict__ topi) {
    __shared__ float mv[48 * 4];   // 3 quarters x 16 rows x top4
    __shared__ int   mi[48 * 4];

    const int tid  = threadIdx.x;
    const int w    = tid >> 6;     // code quarter 0..3
    const int l    = tid & 63;
    const int c16  = l & 15;
    const int quad = l >> 4;
    const int row0 = blockIdx.x * 16;

    // ---- X fragments (B-operand): 16 rows, hi only, K=256 (32 VGPR) ----
    s16x8 xh[8];
    {
        const float* xrow = X + (size_t)(row0 + c16) * DIM + quad * 8;
#pragma unroll
        for (int ks = 0; ks < 8; ++ks) {
            float4 f0 = *(const float4*)(xrow + ks * 32);
            float4 f1 = *(const float4*)(xrow + ks * 32 + 4);
            float fs[8] = {f0.x, f0.y, f0.z, f0.w, f1.x, f1.y, f1.z, f1.w};
#pragma unroll
            for (int j = 0; j < 8; ++j) xh[ks][j] = (short)bf_rne(fs[j]);
        }
    }

    float tva[4];
    int   tia[4];
#pragma unroll
    for (int s = 0; s < 4; ++s) { tva[s] = INFINITY; tia[s] = 0x7fffffff; }

    // ---- main loop: 16 code-tiles of this wave's quarter, no barriers ----
    const int rot = blockIdx.x & 15;
    for (int t0 = 0; t0 < 16; ++t0) {
        const int c = (t0 + rot) & 15;
        const int base = c * 64 + w * 16;
        // A-fragments for codes [base, base+16): lane holds A[m=c16][k=quad*8+j]
        const unsigned short* ep = Eh + (size_t)(base + c16) * DIM + quad * 8;
        s16x8 ch[8];
#pragma unroll
        for (int ks = 0; ks < 8; ++ks) ch[ks] = *(const s16x8*)(ep + ks * 32);
        f32x4 ce = {0.f, 0.f, 0.f, 0.f};
        f32x4 co = {0.f, 0.f, 0.f, 0.f};
#pragma unroll
        for (int ks = 0; ks < 8; ks += 2) {
            ce = __builtin_amdgcn_mfma_f32_16x16x32_bf16(ch[ks],     xh[ks],     ce, 0, 0, 0);
            co = __builtin_amdgcn_mfma_f32_16x16x32_bf16(ch[ks + 1], xh[ks + 1], co, 0, 0, 0);
        }
        f32x4 e2v = *(const f32x4*)(e2g + base + quad * 4);
#pragma unroll
        for (int r = 0; r < 4; ++r) {
            const int code = base + quad * 4 + r;
            ins4(fmaf(-2.0f, ce[r] + co[r], e2v[r]), code, tva, tia);
        }
    }

    // merge top-4 across the 4 quads holding the same x-row (lanes l^16, l^32)
#pragma unroll
    for (int st = 16; st <= 32; st <<= 1) {
        float ov[4]; int oi[4];
#pragma unroll
        for (int s = 0; s < 4; ++s) {
            ov[s] = __shfl_xor(tva[s], st, 64);
            oi[s] = __shfl_xor(tia[s], st, 64);
        }
#pragma unroll
        for (int s = 0; s < 4; ++s) ins4(ov[s], oi[s], tva, tia);
    }

    // merge the 4 code-quarters (exact, order-independent lex top-4) via LDS
    if (w >= 1 && quad == 0) {
        const int sa = (w - 1) * 16 + c16;
#pragma unroll
        for (int s = 0; s < 4; ++s) { mv[sa * 4 + s] = tva[s]; mi[sa * 4 + s] = tia[s]; }
    }
    __syncthreads();
    if (w == 0 && quad == 0) {
#pragma unroll
        for (int g2 = 0; g2 < 3; ++g2) {
            const int sa = g2 * 16 + c16;
#pragma unroll
            for (int s = 0; s < 4; ++s) ins4(mv[sa * 4 + s], mi[sa * 4 + s], tva, tia);
        }
        const int r = row0 + c16;
#pragma unroll
        for (int s = 0; s < 4; ++s) {
            topv[r * 4 + s] = tva[s];
            topi[r * 4 + s] = tia[s];
        }
    }
}

// ---------------------------------------------------------------------------
// Decide + gather (R2-proven thread-per-row structure): 64 rows/block.
// Threads 0..63 decide their row — rescue paths run 64-wide SIMT-parallel
// (the R9 fix: fused version ran them on 16 lanes with the whole block
// barrier-parked). Then all 256 threads gather with coalesced float4 writes.
__global__ __launch_bounds__(256) void decide_gather_kernel(const float* __restrict__ X,
                                                            const float* __restrict__ E,
                                                            const float* __restrict__ e2g,
                                                            const float* __restrict__ topv,
                                                            const int* __restrict__ topi,
                                                            float* __restrict__ out0,
                                                            float* __restrict__ out1,
                                                            float* __restrict__ out2) {
    __shared__ int sidx[64];
    const int tid  = threadIdx.x;
    const int row0 = blockIdx.x * 64;
    if (tid < 64) {
        const int r = row0 + tid;
        float tv[4]; int ti[4];
#pragma unroll
        for (int s = 0; s < 4; ++s) { tv[s] = topv[r * 4 + s]; ti[s] = topi[r * 4 + s]; }

        int best = ti[0];
        if (!(tv[1] > tv[0] + DELTA)) {
            const float* xr = X + (size_t)r * DIM;
            const float x2v = x2_exact(xr);
            float bq = INFINITY; int bi = 0x7fffffff;
            for (int cnd = 0; cnd < 4; ++cnd) {
                if (tv[cnd] <= tv[0] + DELTA) {
                    const int k = ti[cnd];
                    const float* er = E + (size_t)k * DIM;
                    float dot = 0.f;
                    for (int d = 0; d < DIM; d += 4) {   // sequential fp32 chain
                        float4 xv = *(const float4*)(xr + d);
                        float4 ev = *(const float4*)(er + d);
                        dot = fmaf(xv.x, ev.x, dot);
                        dot = fmaf(xv.y, ev.y, dot);
                        dot = fmaf(xv.z, ev.z, dot);
                        dot = fmaf(xv.w, ev.w, dot);
                    }
                    float t1 = e2g[k] - 2.0f * dot;   // numpy elementwise rounding
                    float q  = t1 + x2v;
                    if (q < bq || (q == bq && k < bi)) { bq = q; bi = k; }
                }
            }
            best = bi;
        }
        sidx[tid] = best;
        out2[r] = (float)best;
    }
    __syncthreads();
#pragma unroll
    for (int it = 0; it < 16; ++it) {
        int f = tid + it * 256;
        int rr = f >> 6;
        int pp = f & 63;
        int ix = sidx[rr];
        float4 v = *(const float4*)(E + (size_t)ix * DIM + pp * 4);
        size_t o = (size_t)(row0 + rr) * DIM + (size_t)pp * 4;
        *(float4*)(out0 + o) = v;
        *(float4*)(out1 + o) = v;
    }
}

// ---------------------------------------------------------------------------
extern "C" void kernel_launch(void* const* d_in, const int* in_sizes, int n_in,
                              void* d_out, int out_size, void* d_ws, size_t ws_size,
                              hipStream_t stream) {
    const float* X = (const float*)d_in[0];
    const float* E = (const float*)d_in[1];

    // ws layout (all 16B-aligned): ~1.6 MB total
    float* e2 = (float*)d_ws;                              // 1024 f
    unsigned short* Eh = (unsigned short*)(e2 + KCODES);   // 262144 us
    float* topv = (float*)(Eh + KCODES * DIM);             // 131072 f
    int*   topi = (int*)(topv + N_ROWS * 4);               // 131072 i

    float* out0 = (float*)d_out;
    float* out1 = out0 + (size_t)N_ROWS * DIM;
    float* out2 = out1 + (size_t)N_ROWS * DIM;

    prep_kernel<<<dim3(KCODES / 4), dim3(256), 0, stream>>>(E, e2, Eh);
    vq_screen_kernel<<<dim3(N_ROWS / 16), dim3(256), 0, stream>>>(X, Eh, e2,
                                                                  topv, topi);
    decide_gather_kernel<<<dim3(N_ROWS / 64), dim3(256), 0, stream>>>(X, E, e2,
                                                                      topv, topi,
                                                                      out0, out1, out2);
}

// Round 10
// 198.649 us; speedup vs baseline: 1.6911x; 1.3042x over previous
//
#include <hip/hip_runtime.h>
#include <math.h>

// Problem constants (fixed by reference: B=32,T=1024,D=256,K=1024)
#define N_ROWS 32768
#define DIM    256
#define KCODES 1024
// Screen is single-pass bf16 (s~ = e2 - 2*xh.eh). Score error: sigma ~2.8e-5,
// max over 3.4e7 samples ~1.5e-4; plus numpy fp32 rounding band ~6e-5.
// DELTA = 5e-4 covers flips at >10 sigma; ambiguous rows get exact fp32
// rescore (R2-proven numpy-rounding path).
#define DELTA  5.0e-4f

typedef float f32x4 __attribute__((ext_vector_type(4)));
typedef short s16x8 __attribute__((ext_vector_type(8)));

__device__ inline unsigned short bf_rne(float f) {
    unsigned u = __float_as_uint(f);
    return (unsigned short)((u + 0x7FFFu + ((u >> 16) & 1u)) >> 16);
}

// BRANCHLESS lex sorted-insert of (v,ix) into ascending top-4 (ties -> lower
// index). Compare-exchange walk; insertion-order independent.
__device__ inline void ins4(float v, int ix, float (&tv)[4], int (&ti)[4]) {
#pragma unroll
    for (int s = 0; s < 4; ++s) {
        bool better = (v < tv[s]) || (v == tv[s] && ix < ti[s]);
        float dv = better ? tv[s] : v;   // displaced element continues down
        int   di = better ? ti[s] : ix;
        tv[s] = better ? v : tv[s];
        ti[s] = better ? ix : ti[s];
        v = dv; ix = di;
    }
}

// async global->LDS, 16B per lane. LDS dest = wave-uniform base + lane*16 (HW
// rule); global source is per-lane. Consumes ZERO VGPRs for the data — this is
// the R10 fix: R9's VGPR-minimizing allocator (VGPR_Count=44) re-rolled the
// register operand stream into serial load->waitcnt->MFMA steps.
__device__ __forceinline__ void gl_lds16(const void* gp, void* lp) {
    __builtin_amdgcn_global_load_lds(
        (__attribute__((address_space(1))) void*)(void*)gp,
        (__attribute__((address_space(3))) void*)lp, 16, 0, 0);
}

// ---------------------------------------------------------------------------
// E prep only (e2 pairwise + bf16 hi of E) — verbatim R2-proven body.
__global__ __launch_bounds__(256) void prep_kernel(const float* __restrict__ E,
                                                   float* __restrict__ e2,
                                                   unsigned short* __restrict__ Eh) {
    __shared__ float sq[4][260];
    const int wave = threadIdx.x >> 6;
    const int lane = threadIdx.x & 63;
    const int row = blockIdx.x * 4 + wave;
    const float4* rp = (const float4*)(E + (size_t)row * DIM);
    float4 v = rp[lane];
    sq[wave][lane * 4 + 0] = v.x * v.x;
    sq[wave][lane * 4 + 1] = v.y * v.y;
    sq[wave][lane * 4 + 2] = v.z * v.z;
    sq[wave][lane * 4 + 3] = v.w * v.w;
    float fs[4] = {v.x, v.y, v.z, v.w};
    ushort4 hv;
    unsigned short* hp = (unsigned short*)&hv;
#pragma unroll
    for (int j = 0; j < 4; ++j) hp[j] = bf_rne(fs[j]);
    *(ushort4*)(Eh + (size_t)row * DIM + lane * 4) = hv;
    if (lane < 8) {
#pragma clang fp contract(off)
        const int j = lane;
        float rA = sq[wave][j];
#pragma unroll
        for (int m = 1; m < 16; ++m) rA += sq[wave][8 * m + j];
        float rB = sq[wave][128 + j];
#pragma unroll
        for (int m = 1; m < 16; ++m) rB += sq[wave][128 + 8 * m + j];
        rA = rA + __shfl_xor(rA, 1, 64); rA = rA + __shfl_xor(rA, 2, 64);
        rA = rA + __shfl_xor(rA, 4, 64);
        rB = rB + __shfl_xor(rB, 1, 64); rB = rB + __shfl_xor(rB, 2, 64);
        rB = rB + __shfl_xor(rB, 4, 64);
        if (j == 0) e2[row] = rA + rB;
    }
}

// Exact serial replica of the wave-parallel numpy-pairwise row sum-of-squares.
__device__ float x2_exact(const float* __restrict__ xr) {
#pragma clang fp contract(off)
    float rr[16];
#pragma unroll
    for (int j = 0; j < 8; ++j) {
        float a = xr[j] * xr[j];
#pragma unroll
        for (int m = 1; m < 16; ++m) { float t = xr[8 * m + j]; float s = t * t; a += s; }
        rr[j] = a;
        float b = xr[128 + j] * xr[128 + j];
#pragma unroll
        for (int m = 1; m < 16; ++m) { float t = xr[128 + 8 * m + j]; float s = t * t; b += s; }
        rr[8 + j] = b;
    }
    float a01 = rr[0] + rr[1], a23 = rr[2] + rr[3];
    float a45 = rr[4] + rr[5], a67 = rr[6] + rr[7];
    float A = (a01 + a23) + (a45 + a67);
    float b01 = rr[8] + rr[9], b23 = rr[10] + rr[11];
    float b45 = rr[12] + rr[13], b67 = rr[14] + rr[15];
    float Bt = (b01 + b23) + (b45 + b67);
    return A + Bt;
}

// ---------------------------------------------------------------------------
// SCREEN (R10): LDS-pipelined operand stream, counted-vmcnt barrier loop.
// 64 rows/block, 4 waves x 16 rows each; all waves sweep all 64 16-code tiles.
// Tiles staged in FRAGMENT ORDER (R1's proven layout: lane-linear ds_read_b128
// -> zero bank conflicts, zero swizzle) into a 3-buffer 8KB LDS ring via
// global_load_lds (zero VGPR), 2 tiles prefetch depth. Per tile: counted
// s_waitcnt vmcnt(2) (never 0 — loads stay in flight across the barrier, the
// guide's T4) + raw s_barrier. Each wave covers ALL codes for its own rows ->
// quad-shfl merge only, no cross-wave merge. Numerics identical to R9 (same
// fragments, same even/odd MFMA order, same ins4) -> bit-identical topv/topi.
__global__ __launch_bounds__(256) void vq_screen_kernel(const float* __restrict__ X,
                                                        const unsigned short* __restrict__ Eh,
                                                        const float* __restrict__ e2g,
                                                        float* __restrict__ topv,
                                                        int* __restrict__ topi) {
    __shared__ __align__(16) short buf[3][4096];   // 3 x 8KB tile ring
    __shared__ __align__(16) float e2_lds[KCODES]; // 4KB

    const int tid  = threadIdx.x;
    const int w    = tid >> 6;     // wave 0..3 (owns rows w*16..w*16+15)
    const int l    = tid & 63;
    const int c16  = l & 15;
    const int quad = l >> 4;
    const int row0 = blockIdx.x * 64;

    // e2 -> LDS (async; drained by first vmcnt(2)+barrier). Wave w stages
    // floats [w*256, w*256+256): per-lane src, uniform dest + lane*16B.
    gl_lds16(e2g + w * 256 + l * 4, &e2_lds[w * 256]);

    // ---- X fragments (B-operand): 16 rows of wave w, hi only, K=256 ----
    s16x8 xh[8];
    {
        const float* xrow = X + (size_t)(row0 + w * 16 + c16) * DIM + quad * 8;
#pragma unroll
        for (int ks = 0; ks < 8; ++ks) {
            float4 f0 = *(const float4*)(xrow + ks * 32);
            float4 f1 = *(const float4*)(xrow + ks * 32 + 4);
            float fs[8] = {f0.x, f0.y, f0.z, f0.w, f1.x, f1.y, f1.z, f1.w};
#pragma unroll
            for (int j = 0; j < 8; ++j) xh[ks][j] = (short)bf_rne(fs[j]);
        }
    }

    // stage tile t (codes [t*16, t*16+16)) into buf[t%3], fragment order:
    // group ks (0..7) holds lane-l data = row t*16+(l&15), cols ks*32+(l>>4)*8.
    // Wave w stages ks in {w, w+4}: 2 gl_lds16 per wave per tile.
    auto stage = [&](int t) {
        const unsigned short* Ehc = Eh + (size_t)(t * 16 + c16) * DIM + quad * 8;
        short* bp = &buf[t % 3][0];
#pragma unroll
        for (int gg = 0; gg < 2; ++gg) {
            const int ks = w + gg * 4;
            gl_lds16(Ehc + ks * 32, bp + ks * 512);
        }
    };

    stage(0);
    stage(1);

    float tva[4];
    int   tia[4];
#pragma unroll
    for (int s = 0; s < 4; ++s) { tva[s] = INFINITY; tia[s] = 0x7fffffff; }

    for (int t = 0; t < 64; ++t) {
        // wait MY stage(t) loads (stage(t+1)'s 2 stay in flight), then sync
        // all waves. Raw s_barrier: no implicit vmcnt(0) drain (T4).
        asm volatile("s_waitcnt vmcnt(2)" ::: "memory");
        __builtin_amdgcn_s_barrier();
        __builtin_amdgcn_sched_barrier(0);
        if (t < 62) stage(t + 2);   // refill ring: buf[(t+2)%3] last read at t-1

        const short* bp = &buf[t % 3][0];
        s16x8 ch[8];
#pragma unroll
        for (int ks = 0; ks < 8; ++ks)
            ch[ks] = *(const s16x8*)(bp + ks * 512 + l * 8);   // lane-linear b128

        f32x4 ce = {0.f, 0.f, 0.f, 0.f};
        f32x4 co = {0.f, 0.f, 0.f, 0.f};
#pragma unroll
        for (int ks = 0; ks < 8; ks += 2) {
            ce = __builtin_amdgcn_mfma_f32_16x16x32_bf16(ch[ks],     xh[ks],     ce, 0, 0, 0);
            co = __builtin_amdgcn_mfma_f32_16x16x32_bf16(ch[ks + 1], xh[ks + 1], co, 0, 0, 0);
        }
        f32x4 e2v = *(const f32x4*)&e2_lds[t * 16 + quad * 4];
#pragma unroll
        for (int r = 0; r < 4; ++r) {
            const int code = t * 16 + quad * 4 + r;
            ins4(fmaf(-2.0f, ce[r] + co[r], e2v[r]), code, tva, tia);
        }
    }

    // merge top-4 across the 4 quads holding the same x-row (lanes l^16, l^32)
#pragma unroll
    for (int st = 16; st <= 32; st <<= 1) {
        float ov[4]; int oi[4];
#pragma unroll
        for (int s = 0; s < 4; ++s) {
            ov[s] = __shfl_xor(tva[s], st, 64);
            oi[s] = __shfl_xor(tia[s], st, 64);
        }
#pragma unroll
        for (int s = 0; s < 4; ++s) ins4(ov[s], oi[s], tva, tia);
    }

    if (quad == 0) {
        const int r = row0 + w * 16 + c16;
#pragma unroll
        for (int s = 0; s < 4; ++s) {
            topv[r * 4 + s] = tva[s];
            topi[r * 4 + s] = tia[s];
        }
    }
}

// ---------------------------------------------------------------------------
// Decide + gather (R2/R9-proven thread-per-row structure): 64 rows/block.
__global__ __launch_bounds__(256) void decide_gather_kernel(const float* __restrict__ X,
                                                            const float* __restrict__ E,
                                                            const float* __restrict__ e2g,
                                                            const float* __restrict__ topv,
                                                            const int* __restrict__ topi,
                                                            float* __restrict__ out0,
                                                            float* __restrict__ out1,
                                                            float* __restrict__ out2) {
    __shared__ int sidx[64];
    const int tid  = threadIdx.x;
    const int row0 = blockIdx.x * 64;
    if (tid < 64) {
        const int r = row0 + tid;
        float tv[4]; int ti[4];
#pragma unroll
        for (int s = 0; s < 4; ++s) { tv[s] = topv[r * 4 + s]; ti[s] = topi[r * 4 + s]; }

        int best = ti[0];
        if (!(tv[1] > tv[0] + DELTA)) {
            const float* xr = X + (size_t)r * DIM;
            const float x2v = x2_exact(xr);
            float bq = INFINITY; int bi = 0x7fffffff;
            for (int cnd = 0; cnd < 4; ++cnd) {
                if (tv[cnd] <= tv[0] + DELTA) {
                    const int k = ti[cnd];
                    const float* er = E + (size_t)k * DIM;
                    float dot = 0.f;
                    for (int d = 0; d < DIM; d += 4) {   // sequential fp32 chain
                        float4 xv = *(const float4*)(xr + d);
                        float4 ev = *(const float4*)(er + d);
                        dot = fmaf(xv.x, ev.x, dot);
                        dot = fmaf(xv.y, ev.y, dot);
                        dot = fmaf(xv.z, ev.z, dot);
                        dot = fmaf(xv.w, ev.w, dot);
                    }
                    float t1 = e2g[k] - 2.0f * dot;   // numpy elementwise rounding
                    float q  = t1 + x2v;
                    if (q < bq || (q == bq && k < bi)) { bq = q; bi = k; }
                }
            }
            best = bi;
        }
        sidx[tid] = best;
        out2[r] = (float)best;
    }
    __syncthreads();
#pragma unroll
    for (int it = 0; it < 16; ++it) {
        int f = tid + it * 256;
        int rr = f >> 6;
        int pp = f & 63;
        int ix = sidx[rr];
        float4 v = *(const float4*)(E + (size_t)ix * DIM + pp * 4);
        size_t o = (size_t)(row0 + rr) * DIM + (size_t)pp * 4;
        *(float4*)(out0 + o) = v;
        *(float4*)(out1 + o) = v;
    }
}

// ---------------------------------------------------------------------------
extern "C" void kernel_launch(void* const* d_in, const int* in_sizes, int n_in,
                              void* d_out, int out_size, void* d_ws, size_t ws_size,
                              hipStream_t stream) {
    const float* X = (const float*)d_in[0];
    const float* E = (const float*)d_in[1];

    // ws layout (all 16B-aligned): ~1.6 MB total
    float* e2 = (float*)d_ws;                              // 1024 f
    unsigned short* Eh = (unsigned short*)(e2 + KCODES);   // 262144 us
    float* topv = (float*)(Eh + KCODES * DIM);             // 131072 f
    int*   topi = (int*)(topv + N_ROWS * 4);               // 131072 i

    float* out0 = (float*)d_out;
    float* out1 = out0 + (size_t)N_ROWS * DIM;
    float* out2 = out1 + (size_t)N_ROWS * DIM;

    prep_kernel<<<dim3(KCODES / 4), dim3(256), 0, stream>>>(E, e2, Eh);
    vq_screen_kernel<<<dim3(N_ROWS / 64), dim3(256), 0, stream>>>(X, Eh, e2,
                                                                  topv, topi);
    decide_gather_kernel<<<dim3(N_ROWS / 64), dim3(256), 0, stream>>>(X, E, e2,
                                                                      topv, topi,
                                                                      out0, out1, out2);
}

// Round 11
// 193.113 us; speedup vs baseline: 1.7395x; 1.0287x over previous
//
#include <hip/hip_runtime.h>
#include <math.h>

// Problem constants (fixed by reference: B=32,T=1024,D=256,K=1024)
#define N_ROWS 32768
#define DIM    256
#define KCODES 1024
// Screen is single-pass bf16 (s~ = e2 - 2*xh.eh). Score error: sigma ~2.8e-5,
// max over 3.4e7 samples ~1.5e-4; plus numpy fp32 rounding band ~6e-5.
// DELTA = 5e-4 covers flips at >10 sigma; ambiguous rows get exact fp32
// rescore (R2-proven numpy-rounding path).
#define DELTA  5.0e-4f
// R11: code-space split. Each screen block sweeps KCODES/CSPLIT codes; decide
// merges the CSPLIT partial top-4 lists (exact: disjoint codes, lex total
// order, insertion-order independent).
#define CSPLIT 4
#define TILES  (KCODES / 16 / CSPLIT)   // 16 tiles of 16 codes per block

typedef float f32x4 __attribute__((ext_vector_type(4)));
typedef short s16x8 __attribute__((ext_vector_type(8)));

__device__ inline unsigned short bf_rne(float f) {
    unsigned u = __float_as_uint(f);
    return (unsigned short)((u + 0x7FFFu + ((u >> 16) & 1u)) >> 16);
}

// BRANCHLESS lex sorted-insert of (v,ix) into ascending top-4 (ties -> lower
// index). Compare-exchange walk; insertion-order independent.
__device__ inline void ins4(float v, int ix, float (&tv)[4], int (&ti)[4]) {
#pragma unroll
    for (int s = 0; s < 4; ++s) {
        bool better = (v < tv[s]) || (v == tv[s] && ix < ti[s]);
        float dv = better ? tv[s] : v;   // displaced element continues down
        int   di = better ? ti[s] : ix;
        tv[s] = better ? v : tv[s];
        ti[s] = better ? ix : ti[s];
        v = dv; ix = di;
    }
}

// async global->LDS, 16B per lane. LDS dest = wave-uniform base + lane*16 (HW
// rule); global source is per-lane. Zero VGPRs for the staged data (R10 fix).
__device__ __forceinline__ void gl_lds16(const void* gp, void* lp) {
    __builtin_amdgcn_global_load_lds(
        (__attribute__((address_space(1))) void*)(void*)gp,
        (__attribute__((address_space(3))) void*)lp, 16, 0, 0);
}

// ---------------------------------------------------------------------------
// E prep only (e2 pairwise + bf16 hi of E) — verbatim R2-proven body.
__global__ __launch_bounds__(256) void prep_kernel(const float* __restrict__ E,
                                                   float* __restrict__ e2,
                                                   unsigned short* __restrict__ Eh) {
    __shared__ float sq[4][260];
    const int wave = threadIdx.x >> 6;
    const int lane = threadIdx.x & 63;
    const int row = blockIdx.x * 4 + wave;
    const float4* rp = (const float4*)(E + (size_t)row * DIM);
    float4 v = rp[lane];
    sq[wave][lane * 4 + 0] = v.x * v.x;
    sq[wave][lane * 4 + 1] = v.y * v.y;
    sq[wave][lane * 4 + 2] = v.z * v.z;
    sq[wave][lane * 4 + 3] = v.w * v.w;
    float fs[4] = {v.x, v.y, v.z, v.w};
    ushort4 hv;
    unsigned short* hp = (unsigned short*)&hv;
#pragma unroll
    for (int j = 0; j < 4; ++j) hp[j] = bf_rne(fs[j]);
    *(ushort4*)(Eh + (size_t)row * DIM + lane * 4) = hv;
    if (lane < 8) {
#pragma clang fp contract(off)
        const int j = lane;
        float rA = sq[wave][j];
#pragma unroll
        for (int m = 1; m < 16; ++m) rA += sq[wave][8 * m + j];
        float rB = sq[wave][128 + j];
#pragma unroll
        for (int m = 1; m < 16; ++m) rB += sq[wave][128 + 8 * m + j];
        rA = rA + __shfl_xor(rA, 1, 64); rA = rA + __shfl_xor(rA, 2, 64);
        rA = rA + __shfl_xor(rA, 4, 64);
        rB = rB + __shfl_xor(rB, 1, 64); rB = rB + __shfl_xor(rB, 2, 64);
        rB = rB + __shfl_xor(rB, 4, 64);
        if (j == 0) e2[row] = rA + rB;
    }
}

// Exact serial replica of the wave-parallel numpy-pairwise row sum-of-squares.
__device__ float x2_exact(const float* __restrict__ xr) {
#pragma clang fp contract(off)
    float rr[16];
#pragma unroll
    for (int j = 0; j < 8; ++j) {
        float a = xr[j] * xr[j];
#pragma unroll
        for (int m = 1; m < 16; ++m) { float t = xr[8 * m + j]; float s = t * t; a += s; }
        rr[j] = a;
        float b = xr[128 + j] * xr[128 + j];
#pragma unroll
        for (int m = 1; m < 16; ++m) { float t = xr[128 + 8 * m + j]; float s = t * t; b += s; }
        rr[8 + j] = b;
    }
    float a01 = rr[0] + rr[1], a23 = rr[2] + rr[3];
    float a45 = rr[4] + rr[5], a67 = rr[6] + rr[7];
    float A = (a01 + a23) + (a45 + a67);
    float b01 = rr[8] + rr[9], b23 = rr[10] + rr[11];
    float b45 = rr[12] + rr[13], b67 = rr[14] + rr[15];
    float Bt = (b01 + b23) + (b45 + b67);
    return A + Bt;
}

// ---------------------------------------------------------------------------
// SCREEN (R11 = R10 + CSPLIT grid inflation). R10 post-mortem: grid 512 ->
// only 2 blocks/CU resident (Occupancy 22%) while LDS/VGPR allow 6 — grid was
// the occupancy limiter; 72% of issue slots idle. Here each block sweeps a
// 256-code slice (16 tiles) for its 64 rows: grid 2048 -> ~6 resident
// blocks/CU (LDS 25KB), 75% occupancy ceiling. Tile-loop internals are
// byte-identical to R10 (LDS ring, gl_lds staging in fragment order, counted
// vmcnt(2) + raw s_barrier, even/odd MFMA, branchless ins4).
// Partial top-4 per slice -> topv/topi[h]; decide merges exactly.
__global__ __launch_bounds__(256) void vq_screen_kernel(const float* __restrict__ X,
                                                        const unsigned short* __restrict__ Eh,
                                                        const float* __restrict__ e2g,
                                                        float* __restrict__ topv,
                                                        unsigned short* __restrict__ topi) {
    __shared__ __align__(16) short buf[3][4096];   // 3 x 8KB tile ring
    __shared__ __align__(16) float e2_lds[256];    // this block's e2 slice

    const int tid  = threadIdx.x;
    const int w    = tid >> 6;     // wave 0..3 (owns rows w*16..w*16+15)
    const int l    = tid & 63;
    const int c16  = l & 15;
    const int quad = l >> 4;
    const int bx   = blockIdx.x;
    const int h    = bx & (CSPLIT - 1);       // code slice (adjacent blocks
    const int rb   = bx >> 2;                 //  share X rows -> L2 locality)
    const int row0 = rb * 64;
    const int cbase = h * (KCODES / CSPLIT);  // slice base code

    // e2 slice -> LDS (wave 0, async; visible after first vmcnt+barrier)
    if (w == 0) gl_lds16(e2g + cbase + l * 4, &e2_lds[0]);

    // ---- X fragments (B-operand): 16 rows of wave w, hi only, K=256 ----
    s16x8 xh[8];
    {
        const float* xrow = X + (size_t)(row0 + w * 16 + c16) * DIM + quad * 8;
#pragma unroll
        for (int ks = 0; ks < 8; ++ks) {
            float4 f0 = *(const float4*)(xrow + ks * 32);
            float4 f1 = *(const float4*)(xrow + ks * 32 + 4);
            float fs[8] = {f0.x, f0.y, f0.z, f0.w, f1.x, f1.y, f1.z, f1.w};
#pragma unroll
            for (int j = 0; j < 8; ++j) xh[ks][j] = (short)bf_rne(fs[j]);
        }
    }

    const int rot = rb & (TILES - 1);
    // stage tile-slot t (codes cbase + ct*16 ..): fragment order, wave w
    // stages ks in {w, w+4} (2 gl_lds16/wave/tile).
    auto stage = [&](int t) {
        const int ct = (t + rot) & (TILES - 1);
        const unsigned short* Ehc =
            Eh + (size_t)(cbase + ct * 16 + c16) * DIM + quad * 8;
        short* bp = &buf[t % 3][0];
#pragma unroll
        for (int gg = 0; gg < 2; ++gg) {
            const int ks = w + gg * 4;
            gl_lds16(Ehc + ks * 32, bp + ks * 512);
        }
    };

    stage(0);
    stage(1);

    float tva[4];
    int   tia[4];
#pragma unroll
    for (int s = 0; s < 4; ++s) { tva[s] = INFINITY; tia[s] = 0x7fffffff; }

    for (int t = 0; t < TILES; ++t) {
        // wait MY stage(t) loads (stage(t+1)'s stay in flight); raw barrier
        // (no implicit vmcnt(0) drain — T4).
        asm volatile("s_waitcnt vmcnt(2)" ::: "memory");
        __builtin_amdgcn_s_barrier();
        __builtin_amdgcn_sched_barrier(0);
        if (t < TILES - 2) stage(t + 2);

        const int ct = (t + rot) & (TILES - 1);
        const short* bp = &buf[t % 3][0];
        s16x8 ch[8];
#pragma unroll
        for (int ks = 0; ks < 8; ++ks)
            ch[ks] = *(const s16x8*)(bp + ks * 512 + l * 8);   // lane-linear b128

        f32x4 ce = {0.f, 0.f, 0.f, 0.f};
        f32x4 co = {0.f, 0.f, 0.f, 0.f};
#pragma unroll
        for (int ks = 0; ks < 8; ks += 2) {
            ce = __builtin_amdgcn_mfma_f32_16x16x32_bf16(ch[ks],     xh[ks],     ce, 0, 0, 0);
            co = __builtin_amdgcn_mfma_f32_16x16x32_bf16(ch[ks + 1], xh[ks + 1], co, 0, 0, 0);
        }
        f32x4 e2v = *(const f32x4*)&e2_lds[ct * 16 + quad * 4];
#pragma unroll
        for (int r = 0; r < 4; ++r) {
            const int code = cbase + ct * 16 + quad * 4 + r;
            ins4(fmaf(-2.0f, ce[r] + co[r], e2v[r]), code, tva, tia);
        }
    }

    // merge top-4 across the 4 quads holding the same x-row (lanes l^16, l^32)
#pragma unroll
    for (int st = 16; st <= 32; st <<= 1) {
        float ov[4]; int oi[4];
#pragma unroll
        for (int s = 0; s < 4; ++s) {
            ov[s] = __shfl_xor(tva[s], st, 64);
            oi[s] = __shfl_xor(tia[s], st, 64);
        }
#pragma unroll
        for (int s = 0; s < 4; ++s) ins4(ov[s], oi[s], tva, tia);
    }

    if (quad == 0) {
        const int r = row0 + w * 16 + c16;
        const size_t o = ((size_t)h * N_ROWS + r) * 4;
#pragma unroll
        for (int s = 0; s < 4; ++s) {
            topv[o + s] = tva[s];
            topi[o + s] = (unsigned short)tia[s];   // codes < 1024; all 4
        }                                           // slots always real codes
    }
}

// ---------------------------------------------------------------------------
// Decide + gather (thread-per-row): merge the CSPLIT partial top-4 lists
// (exact — disjoint code sets, lex total order, order-independent), then the
// verbatim R2-proven fast-path/rescue, then coalesced gather.
__global__ __launch_bounds__(256) void decide_gather_kernel(const float* __restrict__ X,
                                                            const float* __restrict__ E,
                                                            const float* __restrict__ e2g,
                                                            const float* __restrict__ topv,
                                                            const unsigned short* __restrict__ topi,
                                                            float* __restrict__ out0,
                                                            float* __restrict__ out1,
                                                            float* __restrict__ out2) {
    __shared__ int sidx[64];
    const int tid  = threadIdx.x;
    const int row0 = blockIdx.x * 64;
    if (tid < 64) {
        const int r = row0 + tid;
        float tv[4]; int ti[4];
#pragma unroll
        for (int s = 0; s < 4; ++s) { tv[s] = INFINITY; ti[s] = 0x7fffffff; }
#pragma unroll
        for (int hh = 0; hh < CSPLIT; ++hh) {
            const size_t o = ((size_t)hh * N_ROWS + r) * 4;
#pragma unroll
            for (int s = 0; s < 4; ++s) ins4(topv[o + s], (int)topi[o + s], tv, ti);
        }

        int best = ti[0];
        if (!(tv[1] > tv[0] + DELTA)) {
            const float* xr = X + (size_t)r * DIM;
            const float x2v = x2_exact(xr);
            float bq = INFINITY; int bi = 0x7fffffff;
            for (int cnd = 0; cnd < 4; ++cnd) {
                if (tv[cnd] <= tv[0] + DELTA) {
                    const int k = ti[cnd];
                    const float* er = E + (size_t)k * DIM;
                    float dot = 0.f;
                    for (int d = 0; d < DIM; d += 4) {   // sequential fp32 chain
                        float4 xv = *(const float4*)(xr + d);
                        float4 ev = *(const float4*)(er + d);
                        dot = fmaf(xv.x, ev.x, dot);
                        dot = fmaf(xv.y, ev.y, dot);
                        dot = fmaf(xv.z, ev.z, dot);
                        dot = fmaf(xv.w, ev.w, dot);
                    }
                    float t1 = e2g[k] - 2.0f * dot;   // numpy elementwise rounding
                    float q  = t1 + x2v;
                    if (q < bq || (q == bq && k < bi)) { bq = q; bi = k; }
                }
            }
            best = bi;
        }
        sidx[tid] = best;
        out2[r] = (float)best;
    }
    __syncthreads();
#pragma unroll
    for (int it = 0; it < 16; ++it) {
        int f = tid + it * 256;
        int rr = f >> 6;
        int pp = f & 63;
        int ix = sidx[rr];
        float4 v = *(const float4*)(E + (size_t)ix * DIM + pp * 4);
        size_t o = (size_t)(row0 + rr) * DIM + (size_t)pp * 4;
        *(float4*)(out0 + o) = v;
        *(float4*)(out1 + o) = v;
    }
}

// ---------------------------------------------------------------------------
extern "C" void kernel_launch(void* const* d_in, const int* in_sizes, int n_in,
                              void* d_out, int out_size, void* d_ws, size_t ws_size,
                              hipStream_t stream) {
    const float* X = (const float*)d_in[0];
    const float* E = (const float*)d_in[1];

    // ws layout (all 16B-aligned): ~3.6 MB total
    float* e2 = (float*)d_ws;                               // 1024 f
    unsigned short* Eh = (unsigned short*)(e2 + KCODES);    // 262144 us (512KB)
    float* topv = (float*)(Eh + KCODES * DIM);              // 4*32768*4 f (2MB)
    unsigned short* topi =
        (unsigned short*)(topv + (size_t)CSPLIT * N_ROWS * 4);  // (1MB)

    float* out0 = (float*)d_out;
    float* out1 = out0 + (size_t)N_ROWS * DIM;
    float* out2 = out1 + (size_t)N_ROWS * DIM;

    prep_kernel<<<dim3(KCODES / 4), dim3(256), 0, stream>>>(E, e2, Eh);
    vq_screen_kernel<<<dim3((N_ROWS / 64) * CSPLIT), dim3(256), 0, stream>>>(X, Eh, e2,
                                                                             topv, topi);
    decide_gather_kernel<<<dim3(N_ROWS / 64), dim3(256), 0, stream>>>(X, E, e2,
                                                                      topv, topi,
                                                                      out0, out1, out2);
}